// Round 1
// baseline (1443.969 us; speedup 1.0000x reference)
//
#include <hip/hip_runtime.h>
#include <hip/hip_bf16.h>
#include <math.h>

// Problem constants
constexpr int BB   = 8;
constexpr int NN   = 4096;
constexpr int MM   = 1024;
constexpr int KK   = 16;
constexpr int CIN  = 3;
constexpr int H1n  = 64;
constexpr int H2n  = 64;
constexpr int COUT = 128;
#define RSQ 0.09f

__device__ __forceinline__ float dist2_exact(float ax, float ay, float az,
                                             float bx, float by, float bz) {
    // (a-b)^2 summed, no fma contraction: match XLA's mul-then-add semantics
    float dx = __fsub_rn(ax, bx);
    float dy = __fsub_rn(ay, by);
    float dz = __fsub_rn(az, bz);
    return __fadd_rn(__fadd_rn(__fmul_rn(dx, dx), __fmul_rn(dy, dy)), __fmul_rn(dz, dz));
}

// ---------------------------------------------------------------------------
// Kernel 1: farthest point sampling. One block per cloud. 256 thr, 16 pts/thr.
// Writes pos_s and batch_s output sections directly.
// ---------------------------------------------------------------------------
__global__ __launch_bounds__(256) void fps_kernel(const float* __restrict__ pos,
                                                  float* __restrict__ pos_s,
                                                  float* __restrict__ batch_s) {
    const int b   = blockIdx.x;
    const int tid = threadIdx.x;
    const int lane = tid & 63;
    const int wave = tid >> 6;
    const float* pb = pos + (size_t)b * NN * 3;

    __shared__ float spx[NN], spy[NN], spz[NN];   // 48 KB
    __shared__ float rv[4];
    __shared__ int   ri[4];

    for (int i = tid; i < NN; i += 256) {
        spx[i] = pb[i * 3 + 0];
        spy[i] = pb[i * 3 + 1];
        spz[i] = pb[i * 3 + 2];
    }
    __syncthreads();

    // registers: 16 strided points per thread (p = tid + k*256)
    float px[16], py[16], pz[16], d[16];
    const float x0 = spx[0], y0 = spy[0], z0 = spz[0];
#pragma unroll
    for (int k = 0; k < 16; k++) {
        int p = tid + k * 256;
        px[k] = spx[p]; py[k] = spy[p]; pz[k] = spz[p];
        d[k] = dist2_exact(px[k], py[k], pz[k], x0, y0, z0);
    }
    if (tid == 0) {
        int o = b * MM;
        pos_s[o * 3 + 0] = x0; pos_s[o * 3 + 1] = y0; pos_s[o * 3 + 2] = z0;
        batch_s[o] = (float)b;
    }

    for (int m = 1; m < MM; m++) {
        // local argmax, tie -> lowest index (k ascending == index ascending)
        float bv = d[0];
        int   bi = tid;
#pragma unroll
        for (int k = 1; k < 16; k++) {
            int p = tid + k * 256;
            if (d[k] > bv) { bv = d[k]; bi = p; }
        }
        // wave butterfly reduce (argmax, tie -> lowest index)
#pragma unroll
        for (int s = 1; s < 64; s <<= 1) {
            float ov = __shfl_xor(bv, s, 64);
            int   oi = __shfl_xor(bi, s, 64);
            if (ov > bv || (ov == bv && oi < bi)) { bv = ov; bi = oi; }
        }
        if (lane == 0) { rv[wave] = bv; ri[wave] = bi; }
        __syncthreads();
        float fv = rv[0];
        int   fi = ri[0];
#pragma unroll
        for (int w = 1; w < 4; w++) {
            float v = rv[w]; int i2 = ri[w];
            if (v > fv || (v == fv && i2 < fi)) { fv = v; fi = i2; }
        }
        const float sx = spx[fi], sy = spy[fi], sz = spz[fi];
        if (tid == 0) {
            int o = b * MM + m;
            pos_s[o * 3 + 0] = sx; pos_s[o * 3 + 1] = sy; pos_s[o * 3 + 2] = sz;
            batch_s[o] = (float)b;
        }
#pragma unroll
        for (int k = 0; k < 16; k++) {
            float nd = dist2_exact(px[k], py[k], pz[k], sx, sy, sz);
            d[k] = fminf(d[k], nd);
        }
        __syncthreads();   // protect rv/ri for next iteration
    }
}

// ---------------------------------------------------------------------------
// Kernel 2: radius neighbors, first-K by index. One wave per query.
// NOTE: self-coincident point still OCCUPIES a slot (removal is a mask later).
// ---------------------------------------------------------------------------
__global__ __launch_bounds__(256) void radius_kernel(const float* __restrict__ pos,
                                                     const float* __restrict__ pos_s,
                                                     int* __restrict__ neigh,
                                                     int* __restrict__ counts) {
    const int q    = blockIdx.x * 4 + (threadIdx.x >> 6);
    const int lane = threadIdx.x & 63;
    const int b    = q >> 10;              // q / MM
    const float qx = pos_s[q * 3 + 0];
    const float qy = pos_s[q * 3 + 1];
    const float qz = pos_s[q * 3 + 2];
    const float* pb = pos + (size_t)b * NN * 3;

    int cnt = 0;
    for (int c = 0; c < NN / 64; c++) {
        int p = c * 64 + lane;
        float x = pb[p * 3 + 0], y = pb[p * 3 + 1], z = pb[p * 3 + 2];
        float d2 = dist2_exact(qx, qy, qz, x, y, z);
        bool val = (d2 <= RSQ);
        unsigned long long msk = __ballot(val);
        if (val) {
            int rank = __popcll(msk & ((1ull << lane) - 1ull));
            int slot = cnt + rank;
            if (slot < KK) neigh[q * KK + slot] = p;
        }
        cnt += __popcll(msk);
        if (cnt >= KK) break;
    }
    if (lane == 0) counts[q] = min(cnt, KK);
}

// ---------------------------------------------------------------------------
// Kernel 3: PointConv MLP (6->64->64->128) + masked max over K+1 edges.
// One block (4 waves) per query; one wave per edge; weights in LDS.
// ---------------------------------------------------------------------------
__global__ __launch_bounds__(256) void mlp_kernel(const float* __restrict__ x,
                                                  const float* __restrict__ pos,
                                                  const float* __restrict__ pos_s,
                                                  const float* __restrict__ W1,
                                                  const float* __restrict__ b1,
                                                  const float* __restrict__ W2,
                                                  const float* __restrict__ b2,
                                                  const float* __restrict__ W3,
                                                  const float* __restrict__ b3,
                                                  const int* __restrict__ neigh,
                                                  const int* __restrict__ counts,
                                                  float* __restrict__ out) {
    __shared__ float sW1[6 * 64];
    __shared__ float sW2[64 * 64];
    __shared__ float sW3[64 * 128];
    __shared__ float sb1[64], sb2[64], sb3[128];
    __shared__ float hbuf[4][64];
    __shared__ float wmax[4][128];

    const int tid  = threadIdx.x;
    const int lane = tid & 63;
    const int wave = tid >> 6;
    const int q    = blockIdx.x;
    const int b    = q >> 10;

    for (int i = tid; i < 6 * 64; i += 256)   sW1[i] = W1[i];
    for (int i = tid; i < 64 * 64; i += 256)  sW2[i] = W2[i];
    for (int i = tid; i < 64 * 128; i += 256) sW3[i] = W3[i];
    if (tid < 64)  sb1[tid] = b1[tid];
    if (tid >= 64 && tid < 128) sb2[tid - 64] = b2[tid - 64];
    if (tid >= 128 && tid < 256) { if (tid - 128 < 128) sb3[tid - 128] = b3[tid - 128]; }
    __syncthreads();

    const float qx = pos_s[q * 3 + 0];
    const float qy = pos_s[q * 3 + 1];
    const float qz = pos_s[q * 3 + 2];
    const int cnt = counts[q];

    float m0 = -INFINITY, m1 = -INFINITY;

    for (int e = wave; e < KK + 1; e += 4) {
        int g;                       // flat source row into x/pos
        if (e < KK) {
            if (e >= cnt) continue;  // empty slot (uniform per wave)
            int p = neigh[q * KK + e];
            g = b * NN + p;
            if (g == q) continue;    // self-loop removal (numeric flat equality)
        } else {
            g = q;                   // added self-loop: row q of x/pos (PyG quirk)
        }
        // 6 features (broadcast loads, wave-uniform address)
        float f0 = x[g * 3 + 0], f1 = x[g * 3 + 1], f2 = x[g * 3 + 2];
        float f3 = pos[g * 3 + 0] - qx;
        float f4 = pos[g * 3 + 1] - qy;
        float f5 = pos[g * 3 + 2] - qz;

        // layer 1: h1[lane]
        float h = sb1[lane];
        h += f0 * sW1[0 * 64 + lane] + f1 * sW1[1 * 64 + lane] + f2 * sW1[2 * 64 + lane]
           + f3 * sW1[3 * 64 + lane] + f4 * sW1[4 * 64 + lane] + f5 * sW1[5 * 64 + lane];
        h = fmaxf(h, 0.0f);
        hbuf[wave][lane] = h;        // wave-lockstep exchange (no barrier needed)

        // layer 2
        float h2 = sb2[lane];
#pragma unroll 8
        for (int j = 0; j < 64; j++) h2 += hbuf[wave][j] * sW2[j * 64 + lane];
        h2 = fmaxf(h2, 0.0f);
        hbuf[wave][lane] = h2;       // all reads of h1 precede this write (lockstep)

        // layer 3 (2 outputs per lane)
        float a0 = sb3[lane], a1 = sb3[64 + lane];
#pragma unroll 8
        for (int j = 0; j < 64; j++) {
            float hv = hbuf[wave][j];
            a0 += hv * sW3[j * 128 + lane];
            a1 += hv * sW3[j * 128 + 64 + lane];
        }
        m0 = fmaxf(m0, a0);
        m1 = fmaxf(m1, a1);
    }

    wmax[wave][lane]      = m0;
    wmax[wave][lane + 64] = m1;
    __syncthreads();
    if (tid < 128) {
        float v = wmax[0][tid];
        v = fmaxf(v, wmax[1][tid]);
        v = fmaxf(v, wmax[2][tid]);
        v = fmaxf(v, wmax[3][tid]);
        out[(size_t)q * COUT + tid] = v;
    }
}

// ---------------------------------------------------------------------------
extern "C" void kernel_launch(void* const* d_in, const int* in_sizes, int n_in,
                              void* d_out, int out_size, void* d_ws, size_t ws_size,
                              hipStream_t stream) {
    const float* x   = (const float*)d_in[0];
    const float* pos = (const float*)d_in[1];
    // d_in[2] = batch (unused: layout is implicit)
    const float* W1 = (const float*)d_in[3];
    const float* b1 = (const float*)d_in[4];
    const float* W2 = (const float*)d_in[5];
    const float* b2 = (const float*)d_in[6];
    const float* W3 = (const float*)d_in[7];
    const float* b3 = (const float*)d_in[8];

    float* outF    = (float*)d_out;
    float* out     = outF;                                  // [B*M, 128]
    float* pos_s   = outF + (size_t)BB * MM * COUT;         // [B*M, 3]
    float* batch_s = pos_s + (size_t)BB * MM * 3;           // [B*M]

    int* neigh  = (int*)d_ws;                               // [B*M, K]
    int* counts = neigh + (size_t)BB * MM * KK;             // [B*M]

    fps_kernel<<<BB, 256, 0, stream>>>(pos, pos_s, batch_s);
    radius_kernel<<<BB * MM / 4, 256, 0, stream>>>(pos, pos_s, neigh, counts);
    mlp_kernel<<<BB * MM, 256, 0, stream>>>(x, pos, pos_s, W1, b1, W2, b2, W3, b3,
                                            neigh, counts, out);
}